// Round 1
// baseline (80.504 us; speedup 1.0000x reference)
//
#include <hip/hip_runtime.h>
#include <hip/hip_bf16.h>

typedef float  f32x4  __attribute__((ext_vector_type(4)));
typedef short  short8 __attribute__((ext_vector_type(8)));

#define KP 800   // K padded (784 -> 25*32)
#define BK 32
#define BM 128

static __device__ __forceinline__ unsigned short f2bf(float f) {
    unsigned int u = __float_as_uint(f);
    unsigned int r = (u + 0x7fffu + ((u >> 16) & 1u)) >> 16;   // RNE
    return (unsigned short)r;
}
static __device__ __forceinline__ float bf2f(unsigned short h) {
    return __uint_as_float(((unsigned int)h) << 16);
}

// Build W_eff = fc1_w o ConvMatrix : [128][800] bf16 (zero-padded past 784)
__global__ __launch_bounds__(256) void weff_prep(
    const float* __restrict__ fc1_w,    // [128][676]
    const float* __restrict__ conv_w,   // [3][3]
    unsigned short* __restrict__ weff)  // [128][KP] bf16
{
    int idx = blockIdx.x * 256 + threadIdx.x;   // o*KP + p
    if (idx >= 128 * KP) return;
    int o = idx / KP, p = idx - o * KP;
    float s = 0.f;
    if (p < 784) {
        int y = p / 28, xx = p - y * 28;
        #pragma unroll
        for (int dr = 0; dr < 3; ++dr) {
            int r = y - dr;
            if (r < 0 || r > 25) continue;
            #pragma unroll
            for (int dc = 0; dc < 3; ++dc) {
                int c = xx - dc;
                if (c < 0 || c > 25) continue;
                s += fc1_w[o * 676 + r * 26 + c] * conv_w[dr * 3 + dc];
            }
        }
    }
    weff[idx] = f2bf(s);
}

// Fused: H = relu(X @ Weff^T + b1); out = H @ fc2^T + b2
__global__ __launch_bounds__(256) void fused_fwd(
    const float* __restrict__ x,              // [B][784]
    const unsigned short* __restrict__ weff,  // [128][KP] bf16
    const float* __restrict__ fc1_b,          // [128]
    const float* __restrict__ fc2_w,          // [10][128]
    const float* __restrict__ fc2_b,          // [10]
    float* __restrict__ out,                  // [B][10]
    int B)
{
    __shared__ unsigned short As[BM][40];     // 32 bf16 + 8 pad (80B rows: 2-way bank alias only)
    __shared__ unsigned short Bs[128][40];
    __shared__ unsigned short Hs[BM][136];    // 128 bf16 + 8 pad (272B rows, 16B-aligned)
    __shared__ float fc2w_s[10 * 128];
    __shared__ float fc2b_s[10];

    const int tid  = threadIdx.x;
    const int m0   = blockIdx.x * BM;
    const int lane = tid & 63;
    const int wid  = tid >> 6;               // 0..3
    const int wr   = wid >> 1, wc = wid & 1; // 2x2 waves, 64x64 each

    for (int i = tid; i < 1280; i += 256) fc2w_s[i] = fc2_w[i];
    if (tid < 10) fc2b_s[tid] = fc2_b[tid];

    f32x4 acc[4][4];
    #pragma unroll
    for (int i = 0; i < 4; ++i)
        #pragma unroll
        for (int j = 0; j < 4; ++j) acc[i][j] = (f32x4)(0.f);

    const int arow = tid >> 3;   // 0..31 (row within 32-row group)
    const int achk = tid & 7;    // float4 chunk within 32-wide K slice

    for (int kt = 0; kt < KP / BK; ++kt) {
        __syncthreads();
        // ---- stage A: 128 rows x 32 k, fp32 -> bf16
        #pragma unroll
        for (int rg = 0; rg < 4; ++rg) {
            int row = rg * 32 + arow;
            int gk  = kt * BK + achk * 4;
            float4 v = make_float4(0.f, 0.f, 0.f, 0.f);
            if (gk < 784 && (m0 + row) < B)
                v = *reinterpret_cast<const float4*>(x + (size_t)(m0 + row) * 784 + gk);
            uint2 pk;
            pk.x = (unsigned int)f2bf(v.x) | ((unsigned int)f2bf(v.y) << 16);
            pk.y = (unsigned int)f2bf(v.z) | ((unsigned int)f2bf(v.w) << 16);
            *reinterpret_cast<uint2*>(&As[row][achk * 4]) = pk;
        }
        // ---- stage B: 128 n-rows x 32 k of W_eff (bf16, already padded)
        #pragma unroll
        for (int cc = 0; cc < 2; ++cc) {
            int id = cc * 256 + tid;
            int n = id >> 2, ch = id & 3;
            uint4 w = *reinterpret_cast<const uint4*>(weff + n * KP + kt * BK + ch * 8);
            *reinterpret_cast<uint4*>(&Bs[n][ch * 8]) = w;
        }
        __syncthreads();
        // ---- fragments + MFMA
        short8 af[4], bf[4];
        const int ko = (lane >> 4) * 8;
        #pragma unroll
        for (int i = 0; i < 4; ++i)
            af[i] = *reinterpret_cast<const short8*>(&As[wr * 64 + i * 16 + (lane & 15)][ko]);
        #pragma unroll
        for (int j = 0; j < 4; ++j)
            bf[j] = *reinterpret_cast<const short8*>(&Bs[wc * 64 + j * 16 + (lane & 15)][ko]);
        #pragma unroll
        for (int i = 0; i < 4; ++i)
            #pragma unroll
            for (int j = 0; j < 4; ++j)
                acc[i][j] = __builtin_amdgcn_mfma_f32_16x16x32_bf16(af[i], bf[j], acc[i][j], 0, 0, 0);
    }

    // ---- epilogue: bias + ReLU -> Hs (bf16)
    __syncthreads();
    #pragma unroll
    for (int i = 0; i < 4; ++i) {
        #pragma unroll
        for (int j = 0; j < 4; ++j) {
            int ncol = wc * 64 + j * 16 + (lane & 15);
            float bias = fc1_b[ncol];
            #pragma unroll
            for (int r = 0; r < 4; ++r) {
                int mrow = wr * 64 + i * 16 + (lane >> 4) * 4 + r;
                float h = acc[i][j][r] + bias;
                h = h > 0.f ? h : 0.f;
                Hs[mrow][ncol] = f2bf(h);
            }
        }
    }
    __syncthreads();

    // ---- stage 2: out[128][10] = Hs @ fc2^T + b2 (fp32 VALU; 1280 dots of K=128)
    for (int it = 0; it < 5; ++it) {
        int idx = it * 256 + tid;            // 0..1279
        int row = idx / 10, j = idx - row * 10;
        if ((m0 + row) < B) {
            float sum = fc2b_s[j];
            const unsigned short* hrow = &Hs[row][0];
            const float* wrow = &fc2w_s[j * 128];
            #pragma unroll 16
            for (int n = 0; n < 128; ++n) sum += bf2f(hrow[n]) * wrow[n];
            out[(size_t)(m0 + row) * 10 + j] = sum;
        }
    }
}

extern "C" void kernel_launch(void* const* d_in, const int* in_sizes, int n_in,
                              void* d_out, int out_size, void* d_ws, size_t ws_size,
                              hipStream_t stream) {
    const float* x      = (const float*)d_in[0];
    const float* conv_w = (const float*)d_in[1];
    const float* fc1_w  = (const float*)d_in[2];
    const float* fc1_b  = (const float*)d_in[3];
    const float* fc2_w  = (const float*)d_in[4];
    const float* fc2_b  = (const float*)d_in[5];
    float* out = (float*)d_out;
    unsigned short* weff = (unsigned short*)d_ws;   // 128*800*2 = 204800 B

    int B = in_sizes[0] / 784;

    weff_prep<<<(128 * KP + 255) / 256, 256, 0, stream>>>(fc1_w, conv_w, weff);

    int nblk = (B + BM - 1) / BM;
    fused_fwd<<<nblk, 256, 0, stream>>>(x, weff, fc1_b, fc2_w, fc2_b, out, B);
}

// Round 2
// 78.323 us; speedup vs baseline: 1.0278x; 1.0278x over previous
//
#include <hip/hip_runtime.h>
#include <hip/hip_bf16.h>

typedef float  f32x4  __attribute__((ext_vector_type(4)));
typedef short  short8 __attribute__((ext_vector_type(8)));

#define KP  800   // K padded (784 -> 25*32)
#define NKT 25
#define BM  64

static __device__ __forceinline__ unsigned short f2bf(float f) {
    unsigned int u = __float_as_uint(f);
    unsigned int r = (u + 0x7fffu + ((u >> 16) & 1u)) >> 16;   // RNE
    return (unsigned short)r;
}
static __device__ __forceinline__ float bf2f(unsigned short h) {
    return __uint_as_float(((unsigned int)h) << 16);
}

// Build W_eff = fc1_w o ConvMatrix : [128][KP] bf16 (zero-padded past 784)
__global__ __launch_bounds__(256) void weff_prep(
    const float* __restrict__ fc1_w,    // [128][676]
    const float* __restrict__ conv_w,   // [3][3]
    unsigned short* __restrict__ weff)  // [128][KP] bf16
{
    int idx = blockIdx.x * 256 + threadIdx.x;   // o*KP + p
    if (idx >= 128 * KP) return;
    int o = idx / KP, p = idx - o * KP;
    float s = 0.f;
    if (p < 784) {
        int y = p / 28, xx = p - y * 28;
        #pragma unroll
        for (int dr = 0; dr < 3; ++dr) {
            int r = y - dr;
            if (r < 0 || r > 25) continue;
            #pragma unroll
            for (int dc = 0; dc < 3; ++dc) {
                int c = xx - dc;
                if (c < 0 || c > 25) continue;
                s += fc1_w[o * 676 + r * 26 + c] * conv_w[dr * 3 + dc];
            }
        }
    }
    weff[idx] = f2bf(s);
}

// Fused: H = relu(X @ Weff^T + b1); out = H @ fc2^T + b2
// No LDS staging for A/B: MFMA fragments load straight from global
// (X rows 128B-chunked; weff L2-resident). 4 waves 2x2, each 32x64.
__global__ __launch_bounds__(256, 4) void fused_fwd(
    const float* __restrict__ x,              // [B][784]
    const unsigned short* __restrict__ weff,  // [128][KP] bf16
    const float* __restrict__ fc1_b,          // [128]
    const float* __restrict__ fc2_w,          // [10][128]
    const float* __restrict__ fc2_b,          // [10]
    float* __restrict__ out,                  // [B][10]
    int B)
{
    __shared__ unsigned short Hs[BM][136];    // 128 bf16 + 8 pad
    __shared__ float fc2w_s[10 * 128];
    __shared__ float fc2b_s[16];

    const int tid  = threadIdx.x;
    const int lane = tid & 63;
    const int wid  = tid >> 6;                // 0..3
    const int wr   = wid >> 1, wc = wid & 1;  // 2x2 waves: 32 rows x 64 cols each
    const int m0   = blockIdx.x * BM;
    const int r16  = lane & 15;
    const int kc   = lane >> 4;               // 0..3 (k-chunk of 8)

    for (int i = tid; i < 1280; i += 256) fc2w_s[i] = fc2_w[i];
    if (tid < 10) fc2b_s[tid] = fc2_b[tid];

    // loop-invariant row pointers (clamped for safety; B=65536 is exact)
    const float* xp[2];
    #pragma unroll
    for (int i = 0; i < 2; ++i) {
        int row = m0 + wr * 32 + i * 16 + r16;
        if (row >= B) row = B - 1;
        xp[i] = x + (size_t)row * 784;
    }
    const unsigned short* wp[4];
    #pragma unroll
    for (int j = 0; j < 4; ++j)
        wp[j] = weff + (size_t)(wc * 64 + j * 16 + r16) * KP;

    f32x4 acc[2][4];
    #pragma unroll
    for (int i = 0; i < 2; ++i)
        #pragma unroll
        for (int j = 0; j < 4; ++j) acc[i][j] = (f32x4)(0.f);

    #pragma unroll 5
    for (int kt = 0; kt < NKT; ++kt) {
        const int gk = kt * 32 + kc * 8;
        const bool valid = (gk < 784);        // only kt==24, kc>=2 invalid

        short8 af[2];
        #pragma unroll
        for (int i = 0; i < 2; ++i) {
            float4 v0 = make_float4(0.f, 0.f, 0.f, 0.f);
            float4 v1 = v0;
            if (valid) {
                v0 = *reinterpret_cast<const float4*>(xp[i] + gk);
                v1 = *reinterpret_cast<const float4*>(xp[i] + gk + 4);
            }
            unsigned int w0 = (unsigned int)f2bf(v0.x) | ((unsigned int)f2bf(v0.y) << 16);
            unsigned int w1 = (unsigned int)f2bf(v0.z) | ((unsigned int)f2bf(v0.w) << 16);
            unsigned int w2 = (unsigned int)f2bf(v1.x) | ((unsigned int)f2bf(v1.y) << 16);
            unsigned int w3 = (unsigned int)f2bf(v1.z) | ((unsigned int)f2bf(v1.w) << 16);
            short8 a;
            reinterpret_cast<unsigned int*>(&a)[0] = w0;
            reinterpret_cast<unsigned int*>(&a)[1] = w1;
            reinterpret_cast<unsigned int*>(&a)[2] = w2;
            reinterpret_cast<unsigned int*>(&a)[3] = w3;
            af[i] = a;
        }

        short8 bfv[4];
        #pragma unroll
        for (int j = 0; j < 4; ++j)
            bfv[j] = *reinterpret_cast<const short8*>(wp[j] + gk);  // weff zero-padded to KP

        #pragma unroll
        for (int i = 0; i < 2; ++i)
            #pragma unroll
            for (int j = 0; j < 4; ++j)
                acc[i][j] = __builtin_amdgcn_mfma_f32_16x16x32_bf16(af[i], bfv[j], acc[i][j], 0, 0, 0);
    }

    // epilogue: bias + ReLU -> Hs (bf16). Unique writer per cell, no pre-barrier needed.
    #pragma unroll
    for (int i = 0; i < 2; ++i) {
        #pragma unroll
        for (int j = 0; j < 4; ++j) {
            int ncol = wc * 64 + j * 16 + r16;
            float bias = fc1_b[ncol];
            #pragma unroll
            for (int r = 0; r < 4; ++r) {
                int mrow = wr * 32 + i * 16 + kc * 4 + r;
                float h = acc[i][j][r] + bias;
                Hs[mrow][ncol] = f2bf(h > 0.f ? h : 0.f);
            }
        }
    }
    __syncthreads();

    // stage 2: out[64][10] = Hs @ fc2^T + b2 (640 dots of K=128, vectorized LDS reads)
    #pragma unroll
    for (int it = 0; it < 3; ++it) {
        int idx = it * 256 + tid;             // 0..767, valid < 640
        if (idx < BM * 10) {
            int row = idx / 10, j = idx - row * 10;
            if ((m0 + row) < B) {
                float sum = fc2b_s[j];
                const float* wrow = &fc2w_s[j * 128];
                #pragma unroll
                for (int n8 = 0; n8 < 16; ++n8) {
                    short8 h = *reinterpret_cast<const short8*>(&Hs[row][n8 * 8]);
                    #pragma unroll
                    for (int k = 0; k < 8; ++k)
                        sum += bf2f(((unsigned short*)&h)[k]) * wrow[n8 * 8 + k];
                }
                out[(size_t)(m0 + row) * 10 + j] = sum;
            }
        }
    }
}

extern "C" void kernel_launch(void* const* d_in, const int* in_sizes, int n_in,
                              void* d_out, int out_size, void* d_ws, size_t ws_size,
                              hipStream_t stream) {
    const float* x      = (const float*)d_in[0];
    const float* conv_w = (const float*)d_in[1];
    const float* fc1_w  = (const float*)d_in[2];
    const float* fc1_b  = (const float*)d_in[3];
    const float* fc2_w  = (const float*)d_in[4];
    const float* fc2_b  = (const float*)d_in[5];
    float* out = (float*)d_out;
    unsigned short* weff = (unsigned short*)d_ws;   // 128*800*2 = 204800 B

    int B = in_sizes[0] / 784;

    weff_prep<<<(128 * KP + 255) / 256, 256, 0, stream>>>(fc1_w, conv_w, weff);

    int nblk = (B + BM - 1) / BM;
    fused_fwd<<<nblk, 256, 0, stream>>>(x, weff, fc1_b, fc2_w, fc2_b, out, B);
}